// Round 2
// baseline (261.481 us; speedup 1.0000x reference)
//
#include <hip/hip_runtime.h>
#include <hip/hip_bf16.h>

#define L_SEQ 2048
#define D_HEAD 64
#define NHEADS 64   // B*H = 4*16
#define L2E 1.44269504088896340736f
#define QSCALE (0.125f * L2E)   // 1/sqrt(64) * log2(e), folded into Q staging

typedef __attribute__((ext_vector_type(8))) __bf16 bf16x8;
typedef __attribute__((ext_vector_type(4))) float f32x4;

// Byte offset into a [rows][64] bf16 tile (128B rows), XOR-swizzled so that
// column-slice b128 reads across rows hit distinct bank groups (G4 fix).
__device__ __forceinline__ int swz(int row, int col) {
    int off = (row << 7) | (col << 1);
    return off ^ ((row & 7) << 4);
}

__device__ __forceinline__ bf16x8 read_frag(const char* lds, int row, int col) {
    return *reinterpret_cast<const bf16x8*>(lds + swz(row, col));
}

// Split staging: load fp32 tile rows into regs (issue early), write bf16
// swizzled LDS later (after compute + barrier).
template <int ROWS>
__device__ __forceinline__ void stage_load(float4* regs, const float* src,
                                           int srcStride, int t) {
    int r0 = t >> 4;
    int c4 = (t & 15) << 2;
#pragma unroll
    for (int i = 0; i < ROWS / 16; ++i)
        regs[i] = *reinterpret_cast<const float4*>(src + (size_t)(r0 + i * 16) * srcStride + c4);
}

template <int ROWS>
__device__ __forceinline__ void stage_write(char* lds, const float4* regs, int t,
                                            float scale) {
    int r0 = t >> 4;
    int c4 = (t & 15) << 2;
#pragma unroll
    for (int i = 0; i < ROWS / 16; ++i) {
        float4 v = regs[i];
        union { __bf16 h[4]; unsigned long long u; } pk;
        pk.h[0] = (__bf16)(v.x * scale);
        pk.h[1] = (__bf16)(v.y * scale);
        pk.h[2] = (__bf16)(v.z * scale);
        pk.h[3] = (__bf16)(v.w * scale);
        *reinterpret_cast<unsigned long long*>(lds + swz(r0 + i * 16, c4)) = pk.u;
    }
}

// -------- Pass 1: l2invl[bh][q] = -log2( sum_k exp2(QSCALE*(Q.K)) ) ---------
__global__ __launch_bounds__(256, 4) void attn_pass1(const float* __restrict__ Q,
                                                     const float* __restrict__ K,
                                                     float* __restrict__ l2invl) {
    __shared__ __align__(16) char ldsQ[64 * 128];
    __shared__ __align__(16) char ldsK[128 * 128];
    __shared__ float red[4][64];

    int bh = blockIdx.x >> 5;            // 32 q-tiles per head
    int q0 = (blockIdx.x & 31) << 6;
    const float* Qh = Q + (size_t)bh * L_SEQ * D_HEAD + (size_t)q0 * D_HEAD;
    const float* Kh = K + (size_t)bh * L_SEQ * D_HEAD;

    int t = threadIdx.x;
    int lane = t & 63;
    int w = t >> 6;          // wave 0..3 owns k-cols [w*32, w*32+32)
    int lg = lane >> 4;
    int ln = lane & 15;

    // prologue: stage Q and first K tile
    {
        float4 qreg[4], kreg[8];
        stage_load<64>(qreg, Qh, D_HEAD, t);
        stage_load<128>(kreg, Kh, D_HEAD, t);
        stage_write<64>(ldsQ, qreg, t, QSCALE);
        stage_write<128>(ldsK, kreg, t, 1.0f);
    }
    __syncthreads();

    float lsum[4][4];
#pragma unroll
    for (int qf = 0; qf < 4; ++qf)
#pragma unroll
        for (int r = 0; r < 4; ++r) lsum[qf][r] = 0.f;

    for (int k0 = 0; k0 < L_SEQ; k0 += 128) {
        // ph1: issue next K tile loads (clamped wrap on last iter)
        int nk0 = (k0 + 128) & (L_SEQ - 1);
        float4 kreg[8];
        stage_load<128>(kreg, Kh + (size_t)nk0 * D_HEAD, D_HEAD, t);

        // ph2: S = Q.K^T (+ exp accumulate)
        f32x4 s[4][2];
#pragma unroll
        for (int qf = 0; qf < 4; ++qf)
#pragma unroll
            for (int kf = 0; kf < 2; ++kf) s[qf][kf] = {0.f, 0.f, 0.f, 0.f};

#pragma unroll
        for (int dc = 0; dc < 2; ++dc) {
            bf16x8 bfr[2];
#pragma unroll
            for (int kf = 0; kf < 2; ++kf)
                bfr[kf] = read_frag(ldsK, w * 32 + kf * 16 + ln, dc * 32 + lg * 8);
#pragma unroll
            for (int qf = 0; qf < 4; ++qf) {
                bf16x8 afr = read_frag(ldsQ, qf * 16 + ln, dc * 32 + lg * 8);
#pragma unroll
                for (int kf = 0; kf < 2; ++kf)
                    s[qf][kf] = __builtin_amdgcn_mfma_f32_16x16x32_bf16(
                        afr, bfr[kf], s[qf][kf], 0, 0, 0);
            }
        }
#pragma unroll
        for (int qf = 0; qf < 4; ++qf)
#pragma unroll
            for (int kf = 0; kf < 2; ++kf)
#pragma unroll
                for (int r = 0; r < 4; ++r)
                    lsum[qf][r] += __builtin_amdgcn_exp2f(s[qf][kf][r]);

        __syncthreads();   // B1: all reads of ldsK done
        stage_write<128>(ldsK, kreg, t, 1.0f);
        __syncthreads();   // B2: next K tile visible
    }

    // row-reduce across the 16 lanes of each quarter-wave group
#pragma unroll
    for (int qf = 0; qf < 4; ++qf)
#pragma unroll
        for (int r = 0; r < 4; ++r) {
            float v = lsum[qf][r];
            v += __shfl_xor(v, 1);
            v += __shfl_xor(v, 2);
            v += __shfl_xor(v, 4);
            v += __shfl_xor(v, 8);
            lsum[qf][r] = v;
        }
    if (ln == 0) {
#pragma unroll
        for (int qf = 0; qf < 4; ++qf)
#pragma unroll
            for (int r = 0; r < 4; ++r)
                red[w][qf * 16 + lg * 4 + r] = lsum[qf][r];
    }
    __syncthreads();
    if (t < 64) {
        float ssum = red[0][t] + red[1][t] + red[2][t] + red[3][t];
        l2invl[(size_t)bh * L_SEQ + q0 + t] = -__log2f(ssum);
    }
}

// -------- Pass 2: Out[d, k-tile] = sum_q V[d,q] * exp2(s[q,k] + l2invl[q]) --
__global__ __launch_bounds__(256, 3) void attn_pass2(const float* __restrict__ Q,
                                                     const float* __restrict__ K,
                                                     const float* __restrict__ V,
                                                     const float* __restrict__ l2invl,
                                                     float* __restrict__ out) {
    __shared__ __align__(16) char ldsK[128 * 128];  // K[k][d]   16 KB
    __shared__ __align__(16) char ldsQ[64 * 128];   // Q[q][d]    8 KB
    __shared__ __align__(16) char ldsV[64 * 128];   // V[d][q]    8 KB
    __shared__ __align__(16) char ldsP[128 * 128];  // P^T[k][q] 16 KB

    int bh = blockIdx.x >> 4;            // 16 k-tiles of 128 per head
    int k0 = (blockIdx.x & 15) << 7;
    const float* Qh = Q + (size_t)bh * L_SEQ * D_HEAD;
    const float* Kh = K + (size_t)bh * L_SEQ * D_HEAD + (size_t)k0 * D_HEAD;
    const float* Vh = V + (size_t)bh * D_HEAD * L_SEQ;
    const float* il = l2invl + (size_t)bh * L_SEQ;
    float* Oh = out + (size_t)bh * D_HEAD * L_SEQ;

    int t = threadIdx.x;
    int lane = t & 63;
    int w = t >> 6;          // wave owns out k-cols [w*32, w*32+32)
    int lg = lane >> 4;
    int ln = lane & 15;

    // prologue: stage K (whole block lifetime), Q0, V0
    {
        float4 kreg[8], qreg[4], vreg[4];
        stage_load<128>(kreg, Kh, D_HEAD, t);
        stage_load<64>(qreg, Qh, D_HEAD, t);
        stage_load<64>(vreg, Vh, L_SEQ, t);
        stage_write<128>(ldsK, kreg, t, 1.0f);
        stage_write<64>(ldsQ, qreg, t, QSCALE);
        stage_write<64>(ldsV, vreg, t, 1.0f);
    }
    __syncthreads();

    f32x4 acc[4][2];
#pragma unroll
    for (int df = 0; df < 4; ++df)
#pragma unroll
        for (int kf = 0; kf < 2; ++kf) acc[df][kf] = {0.f, 0.f, 0.f, 0.f};

    for (int q0 = 0; q0 < L_SEQ; q0 += 64) {
        // ph1: issue bias loads + next Q/V tile loads (wrap-clamped)
        float4 l2i4[4];
#pragma unroll
        for (int qf = 0; qf < 4; ++qf)
            l2i4[qf] = *reinterpret_cast<const float4*>(il + q0 + qf * 16 + lg * 4);
        int nq0 = (q0 + 64) & (L_SEQ - 1);
        float4 qreg[4], vreg[4];
        stage_load<64>(qreg, Qh + (size_t)nq0 * D_HEAD, D_HEAD, t);
        stage_load<64>(vreg, Vh + nq0, L_SEQ, t);

        // ph2a: pre-read V fragments for the PV phase (before staging rewrites V)
        bf16x8 vfr[2][4];
#pragma unroll
        for (int qc = 0; qc < 2; ++qc)
#pragma unroll
            for (int df = 0; df < 4; ++df)
                vfr[qc][df] = read_frag(ldsV, df * 16 + ln, qc * 32 + lg * 8);

        // ph2b: S = Q.K^T with C initialized to l2invl[q] (bias trick)
        f32x4 s[4][2];
#pragma unroll
        for (int qf = 0; qf < 4; ++qf)
#pragma unroll
            for (int kf = 0; kf < 2; ++kf)
                s[qf][kf] = {l2i4[qf].x, l2i4[qf].y, l2i4[qf].z, l2i4[qf].w};

#pragma unroll
        for (int dc = 0; dc < 2; ++dc) {
            bf16x8 bfr[2];
#pragma unroll
            for (int kf = 0; kf < 2; ++kf)
                bfr[kf] = read_frag(ldsK, w * 32 + kf * 16 + ln, dc * 32 + lg * 8);
#pragma unroll
            for (int qf = 0; qf < 4; ++qf) {
                bf16x8 afr = read_frag(ldsQ, qf * 16 + ln, dc * 32 + lg * 8);
#pragma unroll
                for (int kf = 0; kf < 2; ++kf)
                    s[qf][kf] = __builtin_amdgcn_mfma_f32_16x16x32_bf16(
                        afr, bfr[kf], s[qf][kf], 0, 0, 0);
            }
        }

        // ph2c: P^T[k][q] = bf16(exp2(s)) -> LDS
#pragma unroll
        for (int qf = 0; qf < 4; ++qf)
#pragma unroll
            for (int kf = 0; kf < 2; ++kf) {
                union { __bf16 h[4]; unsigned long long u; } pk;
                pk.h[0] = (__bf16)__builtin_amdgcn_exp2f(s[qf][kf][0]);
                pk.h[1] = (__bf16)__builtin_amdgcn_exp2f(s[qf][kf][1]);
                pk.h[2] = (__bf16)__builtin_amdgcn_exp2f(s[qf][kf][2]);
                pk.h[3] = (__bf16)__builtin_amdgcn_exp2f(s[qf][kf][3]);
                int krow = w * 32 + kf * 16 + ln;
                int qcol = qf * 16 + lg * 4;
                *reinterpret_cast<unsigned long long*>(ldsP + swz(krow, qcol)) = pk.u;
            }
        __syncthreads();   // B1: P visible; all Q/V reads complete

        // ph3: PV MFMA (V from regs, P from LDS) + staging writes for next tile
#pragma unroll
        for (int qc = 0; qc < 2; ++qc) {
            bf16x8 pfr[2];
#pragma unroll
            for (int kf = 0; kf < 2; ++kf)
                pfr[kf] = read_frag(ldsP, w * 32 + kf * 16 + ln, qc * 32 + lg * 8);
#pragma unroll
            for (int df = 0; df < 4; ++df)
#pragma unroll
                for (int kf = 0; kf < 2; ++kf)
                    acc[df][kf] = __builtin_amdgcn_mfma_f32_16x16x32_bf16(
                        vfr[qc][df], pfr[kf], acc[df][kf], 0, 0, 0);
        }
        stage_write<64>(ldsQ, qreg, t, QSCALE);
        stage_write<64>(ldsV, vreg, t, 1.0f);
        __syncthreads();   // B2: next Q/V visible; P safe to rewrite
    }

#pragma unroll
    for (int df = 0; df < 4; ++df)
#pragma unroll
        for (int kf = 0; kf < 2; ++kf)
#pragma unroll
            for (int r = 0; r < 4; ++r) {
                int d = df * 16 + lg * 4 + r;
                int k = k0 + w * 32 + kf * 16 + ln;
                Oh[(size_t)d * L_SEQ + k] = acc[df][kf][r];
            }
}

extern "C" void kernel_launch(void* const* d_in, const int* in_sizes, int n_in,
                              void* d_out, int out_size, void* d_ws, size_t ws_size,
                              hipStream_t stream) {
    const float* Q = (const float*)d_in[0];
    const float* K = (const float*)d_in[1];
    const float* V = (const float*)d_in[2];
    float* l2invl = (float*)d_ws;        // NHEADS * L_SEQ floats = 512 KB
    float* out = (float*)d_out;

    attn_pass1<<<dim3(NHEADS * (L_SEQ / 64)), dim3(256), 0, stream>>>(Q, K, l2invl);
    attn_pass2<<<dim3(NHEADS * (L_SEQ / 128)), dim3(256), 0, stream>>>(Q, K, V, l2invl, out);
}

// Round 3
// 187.287 us; speedup vs baseline: 1.3962x; 1.3962x over previous
//
#include <hip/hip_runtime.h>
#include <hip/hip_bf16.h>

#define L_SEQ 2048
#define D_HEAD 64
#define NHEADS 64   // B*H = 4*16
#define L2E 1.44269504088896340736f
#define QSCALE (0.125f * L2E)   // 1/sqrt(64) * log2(e), folded into Q staging

typedef __attribute__((ext_vector_type(8))) __bf16 bf16x8;
typedef __attribute__((ext_vector_type(4))) float f32x4;

// Byte offset into a [rows][64] bf16 tile (128B rows), XOR-swizzled so that
// column-slice b128 reads across rows hit distinct bank groups (G4 fix).
__device__ __forceinline__ int swz(int row, int col) {
    int off = (row << 7) | (col << 1);
    return off ^ ((row & 7) << 4);
}

__device__ __forceinline__ bf16x8 read_frag(const char* lds, int row, int col) {
    return *reinterpret_cast<const bf16x8*>(lds + swz(row, col));
}

// Split staging: load fp32 tile rows into regs (issue early), write bf16
// swizzled LDS later.
template <int ROWS>
__device__ __forceinline__ void stage_load(float4* regs, const float* src,
                                           int srcStride, int t) {
    int r0 = t >> 4;
    int c4 = (t & 15) << 2;
#pragma unroll
    for (int i = 0; i < ROWS / 16; ++i)
        regs[i] = *reinterpret_cast<const float4*>(src + (size_t)(r0 + i * 16) * srcStride + c4);
}

template <int ROWS>
__device__ __forceinline__ void stage_write(char* lds, const float4* regs, int t,
                                            float scale) {
    int r0 = t >> 4;
    int c4 = (t & 15) << 2;
#pragma unroll
    for (int i = 0; i < ROWS / 16; ++i) {
        float4 v = regs[i];
        union { __bf16 h[4]; unsigned long long u; } pk;
        pk.h[0] = (__bf16)(v.x * scale);
        pk.h[1] = (__bf16)(v.y * scale);
        pk.h[2] = (__bf16)(v.z * scale);
        pk.h[3] = (__bf16)(v.w * scale);
        *reinterpret_cast<unsigned long long*>(lds + swz(r0 + i * 16, c4)) = pk.u;
    }
}

// -------- Pass 1: invl[bh][q] = 1 / sum_k exp2(QSCALE*(Q.K)) ----------------
__global__ __launch_bounds__(256, 4) void attn_pass1(const float* __restrict__ Q,
                                                     const float* __restrict__ K,
                                                     float* __restrict__ invl) {
    __shared__ __align__(16) char ldsQ[64 * 128];
    __shared__ __align__(16) char ldsK[128 * 128];
    __shared__ float red[4][64];

    int bh = blockIdx.x >> 5;            // 32 q-tiles per head
    int q0 = (blockIdx.x & 31) << 6;
    const float* Qh = Q + (size_t)bh * L_SEQ * D_HEAD + (size_t)q0 * D_HEAD;
    const float* Kh = K + (size_t)bh * L_SEQ * D_HEAD;

    int t = threadIdx.x;
    int lane = t & 63;
    int w = t >> 6;          // wave 0..3 owns k-cols [w*32, w*32+32)
    int lg = lane >> 4;
    int ln = lane & 15;

    // prologue: stage Q and first K tile
    {
        float4 qreg[4], kreg[8];
        stage_load<64>(qreg, Qh, D_HEAD, t);
        stage_load<128>(kreg, Kh, D_HEAD, t);
        stage_write<64>(ldsQ, qreg, t, QSCALE);
        stage_write<128>(ldsK, kreg, t, 1.0f);
    }
    __syncthreads();

    float lsum[4][4];
#pragma unroll
    for (int qf = 0; qf < 4; ++qf)
#pragma unroll
        for (int r = 0; r < 4; ++r) lsum[qf][r] = 0.f;

    for (int k0 = 0; k0 < L_SEQ; k0 += 128) {
        // issue next K tile loads (wrapped on last iter; redundant but harmless)
        int nk0 = (k0 + 128) & (L_SEQ - 1);
        float4 kreg[8];
        stage_load<128>(kreg, Kh + (size_t)nk0 * D_HEAD, D_HEAD, t);

        // S = Q.K^T
        f32x4 s[4][2];
#pragma unroll
        for (int qf = 0; qf < 4; ++qf)
#pragma unroll
            for (int kf = 0; kf < 2; ++kf) s[qf][kf] = {0.f, 0.f, 0.f, 0.f};

        __builtin_amdgcn_s_setprio(1);
#pragma unroll
        for (int dc = 0; dc < 2; ++dc) {
            bf16x8 bfr[2];
#pragma unroll
            for (int kf = 0; kf < 2; ++kf)
                bfr[kf] = read_frag(ldsK, w * 32 + kf * 16 + ln, dc * 32 + lg * 8);
#pragma unroll
            for (int qf = 0; qf < 4; ++qf) {
                bf16x8 afr = read_frag(ldsQ, qf * 16 + ln, dc * 32 + lg * 8);
#pragma unroll
                for (int kf = 0; kf < 2; ++kf)
                    s[qf][kf] = __builtin_amdgcn_mfma_f32_16x16x32_bf16(
                        afr, bfr[kf], s[qf][kf], 0, 0, 0);
            }
        }
        __builtin_amdgcn_s_setprio(0);
#pragma unroll
        for (int qf = 0; qf < 4; ++qf)
#pragma unroll
            for (int kf = 0; kf < 2; ++kf)
#pragma unroll
                for (int r = 0; r < 4; ++r)
                    lsum[qf][r] += __builtin_amdgcn_exp2f(s[qf][kf][r]);

        __syncthreads();   // B1: all reads of ldsK done
        stage_write<128>(ldsK, kreg, t, 1.0f);
        __syncthreads();   // B2: next K tile visible
    }

    // row-reduce across the 16 lanes of each quarter-wave group
#pragma unroll
    for (int qf = 0; qf < 4; ++qf)
#pragma unroll
        for (int r = 0; r < 4; ++r) {
            float v = lsum[qf][r];
            v += __shfl_xor(v, 1);
            v += __shfl_xor(v, 2);
            v += __shfl_xor(v, 4);
            v += __shfl_xor(v, 8);
            lsum[qf][r] = v;
        }
    if (ln == 0) {
#pragma unroll
        for (int qf = 0; qf < 4; ++qf)
#pragma unroll
            for (int r = 0; r < 4; ++r)
                red[w][qf * 16 + lg * 4 + r] = lsum[qf][r];
    }
    __syncthreads();
    if (t < 64) {
        float ssum = red[0][t] + red[1][t] + red[2][t] + red[3][t];
        invl[(size_t)bh * L_SEQ + q0 + t] = 1.0f / ssum;
    }
}

// -------- Pass 2: Out[d, k-tile] = sum_q V[d,q] * exp2(s[q,k]) * invl[q] ----
// Round-1 structure, minus the S->PV barrier (ldsP is wave-local: wave w
// writes AND reads only rows [w*32, w*32+32)), plus reg-prefetch of Q/V.
__global__ __launch_bounds__(256, 3) void attn_pass2(const float* __restrict__ Q,
                                                     const float* __restrict__ K,
                                                     const float* __restrict__ V,
                                                     const float* __restrict__ invl,
                                                     float* __restrict__ out) {
    __shared__ __align__(16) char ldsK[128 * 128];  // K[k][d]   16 KB
    __shared__ __align__(16) char ldsQ[64 * 128];   // Q[q][d]    8 KB
    __shared__ __align__(16) char ldsV[64 * 128];   // V[d][q]    8 KB
    __shared__ __align__(16) char ldsP[128 * 128];  // P^T[k][q] 16 KB (wave-local rows)

    int bh = blockIdx.x >> 4;            // 16 k-tiles of 128 per head
    int k0 = (blockIdx.x & 15) << 7;
    const float* Qh = Q + (size_t)bh * L_SEQ * D_HEAD;
    const float* Kh = K + (size_t)bh * L_SEQ * D_HEAD + (size_t)k0 * D_HEAD;
    const float* Vh = V + (size_t)bh * D_HEAD * L_SEQ;
    const float* il = invl + (size_t)bh * L_SEQ;
    float* Oh = out + (size_t)bh * D_HEAD * L_SEQ;

    int t = threadIdx.x;
    int lane = t & 63;
    int w = t >> 6;          // wave owns out k-cols [w*32, w*32+32)
    int lg = lane >> 4;
    int ln = lane & 15;

    // prologue: stage K (block lifetime), Q0, V0
    {
        float4 kreg[8], qreg[4], vreg[4];
        stage_load<128>(kreg, Kh, D_HEAD, t);
        stage_load<64>(qreg, Qh, D_HEAD, t);
        stage_load<64>(vreg, Vh, L_SEQ, t);
        stage_write<128>(ldsK, kreg, t, 1.0f);
        stage_write<64>(ldsQ, qreg, t, QSCALE);
        stage_write<64>(ldsV, vreg, t, 1.0f);
    }
    __syncthreads();

    f32x4 acc[4][2];
#pragma unroll
    for (int df = 0; df < 4; ++df)
#pragma unroll
        for (int kf = 0; kf < 2; ++kf) acc[df][kf] = {0.f, 0.f, 0.f, 0.f};

    for (int q0 = 0; q0 < L_SEQ; q0 += 64) {
        // issue invl loads (needed mid-iter) + next Q/V tile loads (wrapped)
        float4 il4[4];
#pragma unroll
        for (int qf = 0; qf < 4; ++qf)
            il4[qf] = *reinterpret_cast<const float4*>(il + q0 + qf * 16 + lg * 4);
        int nq0 = (q0 + 64) & (L_SEQ - 1);
        float4 qreg[4], vreg[4];
        stage_load<64>(qreg, Qh + (size_t)nq0 * D_HEAD, D_HEAD, t);
        stage_load<64>(vreg, Vh + nq0, L_SEQ, t);

        // S = Q.K^T (LDS-only operands)
        f32x4 s[4][2];
#pragma unroll
        for (int qf = 0; qf < 4; ++qf)
#pragma unroll
            for (int kf = 0; kf < 2; ++kf) s[qf][kf] = {0.f, 0.f, 0.f, 0.f};

        __builtin_amdgcn_s_setprio(1);
#pragma unroll
        for (int dc = 0; dc < 2; ++dc) {
            bf16x8 bfr[2];
#pragma unroll
            for (int kf = 0; kf < 2; ++kf)
                bfr[kf] = read_frag(ldsK, w * 32 + kf * 16 + ln, dc * 32 + lg * 8);
#pragma unroll
            for (int qf = 0; qf < 4; ++qf) {
                bf16x8 afr = read_frag(ldsQ, qf * 16 + ln, dc * 32 + lg * 8);
#pragma unroll
                for (int kf = 0; kf < 2; ++kf)
                    s[qf][kf] = __builtin_amdgcn_mfma_f32_16x16x32_bf16(
                        afr, bfr[kf], s[qf][kf], 0, 0, 0);
            }
        }
        __builtin_amdgcn_s_setprio(0);

        // P^T[k][q] = bf16(exp2(s) * invl[q]) -> wave-local LDS rows
#pragma unroll
        for (int qf = 0; qf < 4; ++qf)
#pragma unroll
            for (int kf = 0; kf < 2; ++kf) {
                union { __bf16 h[4]; unsigned long long u; } pk;
                pk.h[0] = (__bf16)(__builtin_amdgcn_exp2f(s[qf][kf][0]) * il4[qf].x);
                pk.h[1] = (__bf16)(__builtin_amdgcn_exp2f(s[qf][kf][1]) * il4[qf].y);
                pk.h[2] = (__bf16)(__builtin_amdgcn_exp2f(s[qf][kf][2]) * il4[qf].z);
                pk.h[3] = (__bf16)(__builtin_amdgcn_exp2f(s[qf][kf][3]) * il4[qf].w);
                int krow = w * 32 + kf * 16 + ln;
                int qcol = qf * 16 + lg * 4;
                *reinterpret_cast<unsigned long long*>(ldsP + swz(krow, qcol)) = pk.u;
            }
        // no barrier: P rows are wave-local; compiler orders via lgkmcnt

        // PV: Out[d,k] += V[d,q-tile] @ P[q-tile,k]
        __builtin_amdgcn_s_setprio(1);
#pragma unroll
        for (int qc = 0; qc < 2; ++qc) {
            bf16x8 pfr[2];
#pragma unroll
            for (int kf = 0; kf < 2; ++kf)
                pfr[kf] = read_frag(ldsP, w * 32 + kf * 16 + ln, qc * 32 + lg * 8);
#pragma unroll
            for (int df = 0; df < 4; ++df) {
                bf16x8 vfr = read_frag(ldsV, df * 16 + ln, qc * 32 + lg * 8);
#pragma unroll
                for (int kf = 0; kf < 2; ++kf)
                    acc[df][kf] = __builtin_amdgcn_mfma_f32_16x16x32_bf16(
                        vfr, pfr[kf], acc[df][kf], 0, 0, 0);
            }
        }
        __builtin_amdgcn_s_setprio(0);

        __syncthreads();   // B1: all reads of ldsQ/ldsV done
        stage_write<64>(ldsQ, qreg, t, QSCALE);
        stage_write<64>(ldsV, vreg, t, 1.0f);
        __syncthreads();   // B2: next Q/V visible
    }

#pragma unroll
    for (int df = 0; df < 4; ++df)
#pragma unroll
        for (int kf = 0; kf < 2; ++kf)
#pragma unroll
            for (int r = 0; r < 4; ++r) {
                int d = df * 16 + lg * 4 + r;
                int k = k0 + w * 32 + kf * 16 + ln;
                Oh[(size_t)d * L_SEQ + k] = acc[df][kf][r];
            }
}

extern "C" void kernel_launch(void* const* d_in, const int* in_sizes, int n_in,
                              void* d_out, int out_size, void* d_ws, size_t ws_size,
                              hipStream_t stream) {
    const float* Q = (const float*)d_in[0];
    const float* K = (const float*)d_in[1];
    const float* V = (const float*)d_in[2];
    float* invl = (float*)d_ws;          // NHEADS * L_SEQ floats = 512 KB
    float* out = (float*)d_out;

    attn_pass1<<<dim3(NHEADS * (L_SEQ / 64)), dim3(256), 0, stream>>>(Q, K, invl);
    attn_pass2<<<dim3(NHEADS * (L_SEQ / 128)), dim3(256), 0, stream>>>(Q, K, V, invl, out);
}

// Round 4
// 160.801 us; speedup vs baseline: 1.6261x; 1.1647x over previous
//
#include <hip/hip_runtime.h>
#include <hip/hip_bf16.h>

#define L_SEQ 2048
#define D_HEAD 64
#define NHEADS 64   // B*H
#define QSCALE (0.125f * 1.44269504088896340736f)  // 1/sqrt(64) * log2(e)

typedef __attribute__((ext_vector_type(8))) __bf16 bf16x8;
typedef __attribute__((ext_vector_type(16))) float f32x16;

// Byte offset into a [rows][64] bf16 tile (128B rows), XOR-swizzled (G4).
__device__ __forceinline__ int swz(int row, int col) {
    int off = (row << 7) | (col << 1);
    return off ^ ((row & 7) << 4);
}
__device__ __forceinline__ bf16x8 read_frag(const char* lds, int row, int col) {
    return *reinterpret_cast<const bf16x8*>(lds + swz(row, col));
}

template <int ROWS>
__device__ __forceinline__ void stage_load(float4* regs, const float* src,
                                           int srcStride, int t) {
    int r0 = t >> 4, c4 = (t & 15) << 2;
#pragma unroll
    for (int i = 0; i < ROWS / 16; ++i)
        regs[i] = *reinterpret_cast<const float4*>(src + (size_t)(r0 + i * 16) * srcStride + c4);
}
template <int ROWS>
__device__ __forceinline__ void stage_write(char* lds, const float4* regs, int t,
                                            float scale) {
    int r0 = t >> 4, c4 = (t & 15) << 2;
#pragma unroll
    for (int i = 0; i < ROWS / 16; ++i) {
        float4 v = regs[i];
        union { __bf16 h[4]; unsigned long long u; } pk;
        pk.h[0] = (__bf16)(v.x * scale);
        pk.h[1] = (__bf16)(v.y * scale);
        pk.h[2] = (__bf16)(v.z * scale);
        pk.h[3] = (__bf16)(v.w * scale);
        *reinterpret_cast<unsigned long long*>(lds + swz(r0 + i * 16, c4)) = pk.u;
    }
}

__device__ __forceinline__ unsigned cvt_pk_bf16(float lo, float hi) {
    unsigned r;
    asm("v_cvt_pk_bf16_f32 %0, %1, %2" : "=v"(r) : "v"(lo), "v"(hi));
    return r;
}

// -------- Pass 1: invl[bh][q] = 1 / sum_k exp2(QSCALE*(Q.K)) ----------------
// 64 q-rows/block; Q A-frags in regs; K streamed via double-buffered LDS.
__global__ __launch_bounds__(256, 3) void attn_pass1(const float* __restrict__ Q,
                                                     const float* __restrict__ K,
                                                     float* __restrict__ invl) {
    __shared__ __align__(16) char lds[2][128 * 128];   // 2 x 16KB K buffers
    __shared__ float red[4][64];

    int bid = blockIdx.x;
    int sb = (bid & 7) * 256 + (bid >> 3);   // bijective XCD swizzle (2048 = 8*256)
    int bh = sb >> 5;
    int q0 = (sb & 31) << 6;
    const float* Qh = Q + (size_t)bh * L_SEQ * D_HEAD + (size_t)q0 * D_HEAD;
    const float* Kh = K + (size_t)bh * L_SEQ * D_HEAD;

    int t = threadIdx.x, lane = t & 63, w = t >> 6;
    int hl = lane >> 5, l31 = lane & 31;

    // prologue: stage Q into lds[0], read A-frags, then stage K tile 0
    {
        float4 qreg[4];
        stage_load<64>(qreg, Qh, D_HEAD, t);
        stage_write<64>(lds[0], qreg, t, QSCALE);
    }
    __syncthreads();
    bf16x8 qfrag[2][4];
#pragma unroll
    for (int qb = 0; qb < 2; ++qb)
#pragma unroll
        for (int m = 0; m < 4; ++m)
            qfrag[qb][m] = read_frag(lds[0], qb * 32 + l31, m * 16 + hl * 8);
    __syncthreads();
    {
        float4 kreg[8];
        stage_load<128>(kreg, Kh, D_HEAD, t);
        stage_write<128>(lds[0], kreg, t, 1.0f);
    }
    __syncthreads();

    float lsum[2][16];
#pragma unroll
    for (int qb = 0; qb < 2; ++qb)
#pragma unroll
        for (int r = 0; r < 16; ++r) lsum[qb][r] = 0.f;

    for (int k0 = 0; k0 < L_SEQ; k0 += 128) {
        int c = (k0 >> 7) & 1;
        const char* kcur = lds[c];
        char* knext = lds[c ^ 1];

        // prefetch next K tile (global -> regs); wrapped on last iter
        int nk0 = (k0 + 128) & (L_SEQ - 1);
        float4 kreg[8];
        stage_load<128>(kreg, Kh + (size_t)nk0 * D_HEAD, D_HEAD, t);

        bf16x8 kfr[4];
#pragma unroll
        for (int m = 0; m < 4; ++m)
            kfr[m] = read_frag(kcur, w * 32 + l31, m * 16 + hl * 8);

        f32x16 s[2];
#pragma unroll
        for (int qb = 0; qb < 2; ++qb)
#pragma unroll
            for (int r = 0; r < 16; ++r) s[qb][r] = 0.f;

        __builtin_amdgcn_s_setprio(1);
#pragma unroll
        for (int m = 0; m < 4; ++m) {
            s[0] = __builtin_amdgcn_mfma_f32_32x32x16_bf16(qfrag[0][m], kfr[m], s[0], 0, 0, 0);
            s[1] = __builtin_amdgcn_mfma_f32_32x32x16_bf16(qfrag[1][m], kfr[m], s[1], 0, 0, 0);
        }
        __builtin_amdgcn_s_setprio(0);

#pragma unroll
        for (int qb = 0; qb < 2; ++qb)
#pragma unroll
            for (int r = 0; r < 16; ++r)
                lsum[qb][r] += __builtin_amdgcn_exp2f(s[qb][r]);

        stage_write<128>(knext, kreg, t, 1.0f);
        __syncthreads();   // single barrier per iter (double-buffered)
    }

    // reduce over the 32 k-lanes of each half-wave
#pragma unroll
    for (int qb = 0; qb < 2; ++qb)
#pragma unroll
        for (int r = 0; r < 16; ++r) {
            float v = lsum[qb][r];
            v += __shfl_xor(v, 1);
            v += __shfl_xor(v, 2);
            v += __shfl_xor(v, 4);
            v += __shfl_xor(v, 8);
            v += __shfl_xor(v, 16);
            lsum[qb][r] = v;
        }
    if (l31 == 0) {
#pragma unroll
        for (int qb = 0; qb < 2; ++qb)
#pragma unroll
            for (int r = 0; r < 16; ++r)
                red[w][qb * 32 + (r & 3) + 8 * (r >> 2) + 4 * hl] = lsum[qb][r];
    }
    __syncthreads();
    if (t < 64) {
        float ssum = red[0][t] + red[1][t] + red[2][t] + red[3][t];
        invl[(size_t)bh * L_SEQ + q0 + t] = 1.0f / ssum;
    }
}

// -------- Pass 2: Out[d, k-tile] = sum_q V[d,q] * exp2(s[q,k]) * invl[q] ----
// k-tile 256/block, 4 waves x 64 k-cols; K-frags in regs; P in regs via
// cvt_pk_bf16 + v_permlane32_swap_b32 (no ldsP); dbuf Q/V, 1 barrier/iter.
__global__ __launch_bounds__(256, 2) void attn_pass2(const float* __restrict__ Q,
                                                     const float* __restrict__ K,
                                                     const float* __restrict__ V,
                                                     const float* __restrict__ invl,
                                                     float* __restrict__ out) {
    __shared__ __align__(16) char lds[32768];
    char* ldsQ0 = lds;            // 8 KB
    char* ldsQ1 = lds + 8192;     // 8 KB
    char* ldsV0 = lds + 16384;    // 8 KB
    char* ldsV1 = lds + 24576;    // 8 KB

    int bid = blockIdx.x;
    int sb = (bid & 7) * 64 + (bid >> 3);    // bijective XCD swizzle (512 = 8*64)
    int bh = sb >> 3;
    int k0 = (sb & 7) << 8;
    const float* Qh = Q + (size_t)bh * L_SEQ * D_HEAD;
    const float* Kh = K + (size_t)bh * L_SEQ * D_HEAD + (size_t)k0 * D_HEAD;
    const float* Vh = V + (size_t)bh * D_HEAD * L_SEQ;
    const float* il = invl + (size_t)bh * L_SEQ;
    float* Oh = out + (size_t)bh * D_HEAD * L_SEQ;

    int t = threadIdx.x, lane = t & 63, w = t >> 6;
    int hl = lane >> 5, l31 = lane & 31;

    // prologue: stage K[256][64] into all 32KB, read frags to regs
    {
        float4 kreg[8];
        stage_load<128>(kreg, Kh, D_HEAD, t);
        stage_write<128>(lds, kreg, t, 1.0f);
        stage_load<128>(kreg, Kh + (size_t)128 * D_HEAD, D_HEAD, t);
        stage_write<128>(lds + 128 * 128, kreg, t, 1.0f);
    }
    __syncthreads();
    bf16x8 kfrag[2][4];
#pragma unroll
    for (int kb = 0; kb < 2; ++kb)
#pragma unroll
        for (int m = 0; m < 4; ++m)
            kfrag[kb][m] = read_frag(lds, w * 64 + kb * 32 + l31, m * 16 + hl * 8);
    __syncthreads();
    // stage Q0 / V0
    {
        float4 qreg[4], vreg[4];
        stage_load<64>(qreg, Qh, D_HEAD, t);
        stage_load<64>(vreg, Vh, L_SEQ, t);
        stage_write<64>(ldsQ0, qreg, t, QSCALE);
        stage_write<64>(ldsV0, vreg, t, 1.0f);
    }
    __syncthreads();

    f32x16 acc[2][2];
#pragma unroll
    for (int db = 0; db < 2; ++db)
#pragma unroll
        for (int kb = 0; kb < 2; ++kb)
#pragma unroll
            for (int r = 0; r < 16; ++r) acc[db][kb][r] = 0.f;

    for (int q0 = 0; q0 < L_SEQ; q0 += 64) {
        int c = (q0 >> 6) & 1;
        const char* qcur = c ? ldsQ1 : ldsQ0;
        const char* vcur = c ? ldsV1 : ldsV0;
        char* qnext = c ? ldsQ0 : ldsQ1;
        char* vnext = c ? ldsV0 : ldsV1;

        // prefetch next Q/V tiles (global -> regs); wrapped on last iter
        int nq0 = (q0 + 64) & (L_SEQ - 1);
        float4 qreg[4], vreg[4];
        stage_load<64>(qreg, Qh + (size_t)nq0 * D_HEAD, D_HEAD, t);
        stage_load<64>(vreg, Vh + nq0, L_SEQ, t);

#pragma unroll
        for (int qb = 0; qb < 2; ++qb) {
            // invl values matching this lane's 16 q-rows
            union { float4 v4[4]; float f[16]; } ilu;
#pragma unroll
            for (int g = 0; g < 4; ++g)
                ilu.v4[g] = *reinterpret_cast<const float4*>(il + q0 + qb * 32 + 8 * g + 4 * hl);

            // S = Q.K^T  (A from LDS, B from regs)
            f32x16 s[2];
#pragma unroll
            for (int kb = 0; kb < 2; ++kb)
#pragma unroll
                for (int r = 0; r < 16; ++r) s[kb][r] = 0.f;

            __builtin_amdgcn_s_setprio(1);
#pragma unroll
            for (int m = 0; m < 4; ++m) {
                bf16x8 afr = read_frag(qcur, qb * 32 + l31, m * 16 + hl * 8);
                s[0] = __builtin_amdgcn_mfma_f32_32x32x16_bf16(afr, kfrag[0][m], s[0], 0, 0, 0);
                s[1] = __builtin_amdgcn_mfma_f32_32x32x16_bf16(afr, kfrag[1][m], s[1], 0, 0, 0);
            }
            __builtin_amdgcn_s_setprio(0);

            // P = exp2(s)*invl -> bf16 frag words in-register (T12)
            bf16x8 pfrag[2][2];
#pragma unroll
            for (int kb = 0; kb < 2; ++kb) {
                float p[16];
#pragma unroll
                for (int r = 0; r < 16; ++r)
                    p[r] = __builtin_amdgcn_exp2f(s[kb][r]) * ilu.f[r];
                unsigned wA[4], wB[4];
#pragma unroll
                for (int g = 0; g < 4; ++g) {
                    wA[g] = cvt_pk_bf16(p[4 * g + 0], p[4 * g + 1]);
                    wB[g] = cvt_pk_bf16(p[4 * g + 2], p[4 * g + 3]);
                }
#pragma unroll
                for (int mm = 0; mm < 2; ++mm) {
                    unsigned a0 = wA[2 * mm], b0 = wA[2 * mm + 1];
                    unsigned a1 = wB[2 * mm], b1 = wB[2 * mm + 1];
                    // D.hi <-> S.lo swap: both outputs are usable frag words
                    asm volatile("v_permlane32_swap_b32 %0, %1" : "+v"(a0), "+v"(b0));
                    asm volatile("v_permlane32_swap_b32 %0, %1" : "+v"(a1), "+v"(b1));
                    union { unsigned u[4]; bf16x8 v; } pk;
                    pk.u[0] = a0;  // j=0,1
                    pk.u[1] = a1;  // j=2,3
                    pk.u[2] = b0;  // j=4,5
                    pk.u[3] = b1;  // j=6,7
                    pfrag[kb][mm] = pk.v;
                }
            }

            // PV: acc[d, k] += V[d, q16] @ P[q16, k]
            __builtin_amdgcn_s_setprio(1);
#pragma unroll
            for (int mm = 0; mm < 2; ++mm)
#pragma unroll
                for (int db = 0; db < 2; ++db) {
                    bf16x8 vfr = read_frag(vcur, db * 32 + l31, qb * 32 + mm * 16 + hl * 8);
#pragma unroll
                    for (int kb = 0; kb < 2; ++kb)
                        acc[db][kb] = __builtin_amdgcn_mfma_f32_32x32x16_bf16(
                            vfr, pfrag[kb][mm], acc[db][kb], 0, 0, 0);
                }
            __builtin_amdgcn_s_setprio(0);
        }

        stage_write<64>(qnext, qreg, t, QSCALE);
        stage_write<64>(vnext, vreg, t, 1.0f);
        __syncthreads();   // single barrier per iter (double-buffered)
    }

#pragma unroll
    for (int db = 0; db < 2; ++db)
#pragma unroll
        for (int kb = 0; kb < 2; ++kb)
#pragma unroll
            for (int r = 0; r < 16; ++r) {
                int d = db * 32 + (r & 3) + 8 * (r >> 2) + 4 * hl;
                int k = k0 + w * 64 + kb * 32 + l31;
                Oh[(size_t)d * L_SEQ + k] = acc[db][kb][r];
            }
}

extern "C" void kernel_launch(void* const* d_in, const int* in_sizes, int n_in,
                              void* d_out, int out_size, void* d_ws, size_t ws_size,
                              hipStream_t stream) {
    const float* Q = (const float*)d_in[0];
    const float* K = (const float*)d_in[1];
    const float* V = (const float*)d_in[2];
    float* invl = (float*)d_ws;          // NHEADS * L_SEQ floats = 512 KB
    float* out = (float*)d_out;

    attn_pass1<<<dim3(NHEADS * (L_SEQ / 64)), dim3(256), 0, stream>>>(Q, K, invl);
    attn_pass2<<<dim3(NHEADS * (L_SEQ / 256)), dim3(256), 0, stream>>>(Q, K, V, invl, out);
}

// Round 5
// 158.485 us; speedup vs baseline: 1.6499x; 1.0146x over previous
//
#include <hip/hip_runtime.h>
#include <hip/hip_bf16.h>

#define L_SEQ 2048
#define D_HEAD 64
#define NHEADS 64   // B*H
#define QSCALE (0.125f * 1.44269504088896340736f)  // 1/sqrt(64) * log2(e)

typedef __attribute__((ext_vector_type(8))) __bf16 bf16x8;
typedef __attribute__((ext_vector_type(16))) float f32x16;

// Byte offset into a [rows][64] bf16 tile (128B rows), XOR-swizzled (G4).
__device__ __forceinline__ int swz(int row, int col) {
    int off = (row << 7) | (col << 1);
    return off ^ ((row & 7) << 4);
}
__device__ __forceinline__ bf16x8 read_frag(const char* lds, int row, int col) {
    return *reinterpret_cast<const bf16x8*>(lds + swz(row, col));
}

// 256-thread staging helpers (pass 1)
template <int ROWS>
__device__ __forceinline__ void stage_load(float4* regs, const float* src,
                                           int srcStride, int t) {
    int r0 = t >> 4, c4 = (t & 15) << 2;
#pragma unroll
    for (int i = 0; i < ROWS / 16; ++i)
        regs[i] = *reinterpret_cast<const float4*>(src + (size_t)(r0 + i * 16) * srcStride + c4);
}
template <int ROWS>
__device__ __forceinline__ void stage_write(char* lds, const float4* regs, int t,
                                            float scale) {
    int r0 = t >> 4, c4 = (t & 15) << 2;
#pragma unroll
    for (int i = 0; i < ROWS / 16; ++i) {
        float4 v = regs[i];
        union { __bf16 h[4]; unsigned long long u; } pk;
        pk.h[0] = (__bf16)(v.x * scale);
        pk.h[1] = (__bf16)(v.y * scale);
        pk.h[2] = (__bf16)(v.z * scale);
        pk.h[3] = (__bf16)(v.w * scale);
        *reinterpret_cast<unsigned long long*>(lds + swz(r0 + i * 16, c4)) = pk.u;
    }
}

// component-wise scaled bf16 pack+write (pass 2 staging)
__device__ __forceinline__ void pack_write(char* lds, int row, int c4, float4 v,
                                           float4 sc) {
    union { __bf16 h[4]; unsigned long long u; } pk;
    pk.h[0] = (__bf16)(v.x * sc.x);
    pk.h[1] = (__bf16)(v.y * sc.y);
    pk.h[2] = (__bf16)(v.z * sc.z);
    pk.h[3] = (__bf16)(v.w * sc.w);
    *reinterpret_cast<unsigned long long*>(lds + swz(row, c4)) = pk.u;
}

__device__ __forceinline__ unsigned cvt_pk_bf16(float lo, float hi) {
    unsigned r;
    asm("v_cvt_pk_bf16_f32 %0, %1, %2" : "=v"(r) : "v"(lo), "v"(hi));
    return r;
}

// -------- Pass 1: invl[bh][q] = 1 / sum_k exp2(QSCALE*(Q.K)) ----------------
// (unchanged from round 4)
__global__ __launch_bounds__(256, 3) void attn_pass1(const float* __restrict__ Q,
                                                     const float* __restrict__ K,
                                                     float* __restrict__ invl) {
    __shared__ __align__(16) char lds[2][128 * 128];   // 2 x 16KB K buffers
    __shared__ float red[4][64];

    int bid = blockIdx.x;
    int sb = (bid & 7) * 256 + (bid >> 3);   // bijective XCD swizzle (2048 = 8*256)
    int bh = sb >> 5;
    int q0 = (sb & 31) << 6;
    const float* Qh = Q + (size_t)bh * L_SEQ * D_HEAD + (size_t)q0 * D_HEAD;
    const float* Kh = K + (size_t)bh * L_SEQ * D_HEAD;

    int t = threadIdx.x, lane = t & 63, w = t >> 6;
    int hl = lane >> 5, l31 = lane & 31;

    {
        float4 qreg[4];
        stage_load<64>(qreg, Qh, D_HEAD, t);
        stage_write<64>(lds[0], qreg, t, QSCALE);
    }
    __syncthreads();
    bf16x8 qfrag[2][4];
#pragma unroll
    for (int qb = 0; qb < 2; ++qb)
#pragma unroll
        for (int m = 0; m < 4; ++m)
            qfrag[qb][m] = read_frag(lds[0], qb * 32 + l31, m * 16 + hl * 8);
    __syncthreads();
    {
        float4 kreg[8];
        stage_load<128>(kreg, Kh, D_HEAD, t);
        stage_write<128>(lds[0], kreg, t, 1.0f);
    }
    __syncthreads();

    float lsum[2][16];
#pragma unroll
    for (int qb = 0; qb < 2; ++qb)
#pragma unroll
        for (int r = 0; r < 16; ++r) lsum[qb][r] = 0.f;

    for (int k0 = 0; k0 < L_SEQ; k0 += 128) {
        int c = (k0 >> 7) & 1;
        const char* kcur = lds[c];
        char* knext = lds[c ^ 1];

        int nk0 = (k0 + 128) & (L_SEQ - 1);
        float4 kreg[8];
        stage_load<128>(kreg, Kh + (size_t)nk0 * D_HEAD, D_HEAD, t);

        bf16x8 kfr[4];
#pragma unroll
        for (int m = 0; m < 4; ++m)
            kfr[m] = read_frag(kcur, w * 32 + l31, m * 16 + hl * 8);

        f32x16 s[2];
#pragma unroll
        for (int qb = 0; qb < 2; ++qb)
#pragma unroll
            for (int r = 0; r < 16; ++r) s[qb][r] = 0.f;

        __builtin_amdgcn_s_setprio(1);
#pragma unroll
        for (int m = 0; m < 4; ++m) {
            s[0] = __builtin_amdgcn_mfma_f32_32x32x16_bf16(qfrag[0][m], kfr[m], s[0], 0, 0, 0);
            s[1] = __builtin_amdgcn_mfma_f32_32x32x16_bf16(qfrag[1][m], kfr[m], s[1], 0, 0, 0);
        }
        __builtin_amdgcn_s_setprio(0);

#pragma unroll
        for (int qb = 0; qb < 2; ++qb)
#pragma unroll
            for (int r = 0; r < 16; ++r)
                lsum[qb][r] += __builtin_amdgcn_exp2f(s[qb][r]);

        stage_write<128>(knext, kreg, t, 1.0f);
        __syncthreads();   // single barrier per iter (double-buffered)
    }

#pragma unroll
    for (int qb = 0; qb < 2; ++qb)
#pragma unroll
        for (int r = 0; r < 16; ++r) {
            float v = lsum[qb][r];
            v += __shfl_xor(v, 1);
            v += __shfl_xor(v, 2);
            v += __shfl_xor(v, 4);
            v += __shfl_xor(v, 8);
            v += __shfl_xor(v, 16);
            lsum[qb][r] = v;
        }
    if (l31 == 0) {
#pragma unroll
        for (int qb = 0; qb < 2; ++qb)
#pragma unroll
            for (int r = 0; r < 16; ++r)
                red[w][qb * 32 + (r & 3) + 8 * (r >> 2) + 4 * hl] = lsum[qb][r];
    }
    __syncthreads();
    if (t < 64) {
        float ssum = red[0][t] + red[1][t] + red[2][t] + red[3][t];
        invl[(size_t)bh * L_SEQ + q0 + t] = 1.0f / ssum;
    }
}

// -------- Pass 2: Out[d, k-tile] = sum_q (V[d,q]*invl[q]) * exp2(s[q,k]) ----
// 512 threads / 8 waves, k-tile 256 (32 k-cols per wave). K-frags in regs;
// P in regs (cvt_pk + permlane32_swap); invl folded into V staging; dbuf Q/V
// with one barrier per q-step. 2 blocks/CU x 8 waves = 4 waves/SIMD.
__global__ __launch_bounds__(512, 4) void attn_pass2(const float* __restrict__ Q,
                                                     const float* __restrict__ K,
                                                     const float* __restrict__ V,
                                                     const float* __restrict__ invl,
                                                     float* __restrict__ out) {
    __shared__ __align__(16) char lds[32768];   // K staging, then Q0/Q1/V0/V1

    int bid = blockIdx.x;
    int sb = (bid & 7) * 64 + (bid >> 3);    // bijective XCD swizzle (512 = 8*64)
    int bh = sb >> 3;
    int k0 = (sb & 7) << 8;
    const float* Qh = Q + (size_t)bh * L_SEQ * D_HEAD;
    const float* Kh = K + (size_t)bh * L_SEQ * D_HEAD + (size_t)k0 * D_HEAD;
    const float* Vh = V + (size_t)bh * D_HEAD * L_SEQ;
    const float* il = invl + (size_t)bh * L_SEQ;
    float* Oh = out + (size_t)bh * D_HEAD * L_SEQ;

    int t = threadIdx.x, lane = t & 63, w = t >> 6;    // w 0..7
    int hl = lane >> 5, l31 = lane & 31;
    int r0 = t >> 4;          // 0..31 (staging row)
    int c4 = (t & 15) << 2;   // staging col group

    // prologue A: stage K[256][64] -> bf16 LDS (32 KB), then frags -> regs
#pragma unroll
    for (int i = 0; i < 8; ++i) {
        float4 v = *reinterpret_cast<const float4*>(Kh + (size_t)(r0 + i * 32) * D_HEAD + c4);
        pack_write(lds, r0 + i * 32, c4, v, make_float4(1.f, 1.f, 1.f, 1.f));
    }
    __syncthreads();
    bf16x8 kfrag[4];
#pragma unroll
    for (int m = 0; m < 4; ++m)
        kfrag[m] = read_frag(lds, w * 32 + l31, m * 16 + hl * 8);
    __syncthreads();

    // prologue B: stage Q0 / V0 (V scaled by invl)
    {
        float4 qa = *reinterpret_cast<const float4*>(Qh + (size_t)r0 * D_HEAD + c4);
        float4 qb = *reinterpret_cast<const float4*>(Qh + (size_t)(r0 + 32) * D_HEAD + c4);
        float4 va = *reinterpret_cast<const float4*>(Vh + (size_t)r0 * L_SEQ + c4);
        float4 vb = *reinterpret_cast<const float4*>(Vh + (size_t)(r0 + 32) * L_SEQ + c4);
        float4 iv = *reinterpret_cast<const float4*>(il + c4);
        float4 qs = make_float4(QSCALE, QSCALE, QSCALE, QSCALE);
        pack_write(lds, r0, c4, qa, qs);
        pack_write(lds, r0 + 32, c4, qb, qs);
        pack_write(lds + 16384, r0, c4, va, iv);
        pack_write(lds + 16384, r0 + 32, c4, vb, iv);
    }
    __syncthreads();

    f32x16 acc[2];
#pragma unroll
    for (int db = 0; db < 2; ++db)
#pragma unroll
        for (int r = 0; r < 16; ++r) acc[db][r] = 0.f;

    for (int q0 = 0; q0 < L_SEQ; q0 += 64) {
        int c = (q0 >> 6) & 1;
        const char* qcur = c ? lds + 8192 : lds;
        const char* vcur = c ? lds + 24576 : lds + 16384;
        char* qnext = c ? lds : lds + 8192;
        char* vnext = c ? lds + 16384 : lds + 24576;

        // prefetch next Q/V tiles + invl (wrapped on last iter)
        int nq0 = (q0 + 64) & (L_SEQ - 1);
        float4 qra = *reinterpret_cast<const float4*>(Qh + (size_t)(nq0 + r0) * D_HEAD + c4);
        float4 qrb = *reinterpret_cast<const float4*>(Qh + (size_t)(nq0 + r0 + 32) * D_HEAD + c4);
        float4 vra = *reinterpret_cast<const float4*>(Vh + (size_t)r0 * L_SEQ + nq0 + c4);
        float4 vrb = *reinterpret_cast<const float4*>(Vh + (size_t)(r0 + 32) * L_SEQ + nq0 + c4);
        float4 ivn = *reinterpret_cast<const float4*>(il + nq0 + c4);

#pragma unroll
        for (int qq = 0; qq < 2; ++qq) {
            // S = Q.K^T (A from LDS, B from regs)
            f32x16 s;
#pragma unroll
            for (int r = 0; r < 16; ++r) s[r] = 0.f;

            __builtin_amdgcn_s_setprio(1);
#pragma unroll
            for (int m = 0; m < 4; ++m) {
                bf16x8 afr = read_frag(qcur, qq * 32 + l31, m * 16 + hl * 8);
                s = __builtin_amdgcn_mfma_f32_32x32x16_bf16(afr, kfrag[m], s, 0, 0, 0);
            }
            __builtin_amdgcn_s_setprio(0);

            // P = exp2(s) -> bf16 frag words in-register (invl already in V)
            float p[16];
#pragma unroll
            for (int r = 0; r < 16; ++r) p[r] = __builtin_amdgcn_exp2f(s[r]);
            unsigned wA[4], wB[4];
#pragma unroll
            for (int g = 0; g < 4; ++g) {
                wA[g] = cvt_pk_bf16(p[4 * g + 0], p[4 * g + 1]);
                wB[g] = cvt_pk_bf16(p[4 * g + 2], p[4 * g + 3]);
            }
            bf16x8 pfrag[2];
#pragma unroll
            for (int mm = 0; mm < 2; ++mm) {
                unsigned a0 = wA[2 * mm], b0 = wA[2 * mm + 1];
                unsigned a1 = wB[2 * mm], b1 = wB[2 * mm + 1];
                asm volatile("v_permlane32_swap_b32 %0, %1" : "+v"(a0), "+v"(b0));
                asm volatile("v_permlane32_swap_b32 %0, %1" : "+v"(a1), "+v"(b1));
                union { unsigned u[4]; bf16x8 v; } pk;
                pk.u[0] = a0;
                pk.u[1] = a1;
                pk.u[2] = b0;
                pk.u[3] = b1;
                pfrag[mm] = pk.v;
            }

            // PV: acc[d, k] += V'[d, q16] @ P[q16, k]
            __builtin_amdgcn_s_setprio(1);
#pragma unroll
            for (int mm = 0; mm < 2; ++mm)
#pragma unroll
                for (int db = 0; db < 2; ++db) {
                    bf16x8 vfr = read_frag(vcur, db * 32 + l31, qq * 32 + mm * 16 + hl * 8);
                    acc[db] = __builtin_amdgcn_mfma_f32_32x32x16_bf16(
                        vfr, pfrag[mm], acc[db], 0, 0, 0);
                }
            __builtin_amdgcn_s_setprio(0);
        }

        // stage next Q/V (V scaled by invl) and flip buffers
        {
            float4 qs = make_float4(QSCALE, QSCALE, QSCALE, QSCALE);
            pack_write(qnext, r0, c4, qra, qs);
            pack_write(qnext, r0 + 32, c4, qrb, qs);
            pack_write(vnext, r0, c4, vra, ivn);
            pack_write(vnext, r0 + 32, c4, vrb, ivn);
        }
        __syncthreads();   // single barrier per q-step
    }

#pragma unroll
    for (int db = 0; db < 2; ++db)
#pragma unroll
        for (int r = 0; r < 16; ++r) {
            int d = db * 32 + (r & 3) + 8 * (r >> 2) + 4 * hl;
            int k = k0 + w * 32 + l31;
            Oh[(size_t)d * L_SEQ + k] = acc[db][r];
        }
}

extern "C" void kernel_launch(void* const* d_in, const int* in_sizes, int n_in,
                              void* d_out, int out_size, void* d_ws, size_t ws_size,
                              hipStream_t stream) {
    const float* Q = (const float*)d_in[0];
    const float* K = (const float*)d_in[1];
    const float* V = (const float*)d_in[2];
    float* invl = (float*)d_ws;          // NHEADS * L_SEQ floats = 512 KB
    float* out = (float*)d_out;

    attn_pass1<<<dim3(NHEADS * (L_SEQ / 64)), dim3(256), 0, stream>>>(Q, K, invl);
    attn_pass2<<<dim3(NHEADS * (L_SEQ / 256)), dim3(512), 0, stream>>>(Q, K, V, invl, out);
}